// Round 1
// baseline (115.018 us; speedup 1.0000x reference)
//
#include <hip/hip_runtime.h>
#include <hip/hip_bf16.h>

// CondLaneHead via bf16 MFMA 16x16x32, 3 layers fused. Round 10.
// 32 instances (4 img x 8), C=64, H=160, W=256, L=40960 px.
//
// r9 -> r10: kill the h relu->LDS->readback round-trip. The D-layout ->
// B-frag conversion is a pure axis 3-cycle (reg c4 -> lane32, lane32 c3 ->
// lane16, lane16 c2 -> reg) and gfx950's two-output permlane swaps do it in
// 2 VALU ops per dword pair:
//   stage1 v_permlane32_swap(a=D[2ks][p], b=D[2ks+1][p]):
//          r0={a_lo,b_lo} r1={a_hi,b_hi}           (c4 -> lane32 axis)
//   stage2 v_permlane16_swap(r0, r1):
//          s0={r0[0:15],r1[0:15],r0[32:47],r1[32:47]} = c2=0 word
//          s1={r0[16:31],r1[16:31],...}             = c2=1 word
// This deletes 8 ds_write_b64 + 4 ds_read_b128 + swizzle addressing + the
// mid-iteration lgkmcnt chain per wave-instance, and frees the 16KB scratch:
// LDS 53248 -> 36864 => 4 blocks/CU (launch_bounds(256,4), VGPR cap 128,
// current use ~68-90 so no spill risk per r8 lesson).
// prep: 64 -> 256 blocks (same work, 8-way split) to cut its latency tail.
//
// Frag layouts (m89/m120-verified): A[m=lane&15][k=(lane>>4)*8+j],
// B[k=(lane>>4)*8+j][n=lane&15], D[row=(lane>>4)*4+r][col=lane&15].
//
// ws per instance (ISTRIDE=18432B):
//   [0,8192)      w0 A-frags, frag(mt,kst)=mt*2+kst, 1KB each (lane*16)
//   [8192,16384)  w1 A-frags, same layout
//   [16384,17668) vec f32: b0[64] wx[64] wy[64] b1[64] w2[64] b2
//   [17668,18432) pad (DMA'd, never read)

#define NP 8513
#define HW 40960
#define ISTRIDE 18432
#define OFF_W1 8192
#define OFF_VEC 16384

typedef __attribute__((ext_vector_type(8))) short bf16x8;
typedef __attribute__((ext_vector_type(4))) float f32x4;
typedef __attribute__((ext_vector_type(2))) unsigned uint2v;

__device__ inline unsigned short f2bf(float f) {
  union { float f; unsigned u; } v; v.f = f;
  unsigned r = v.u + 0x7fffu + ((v.u >> 16) & 1u);   // RNE
  return (unsigned short)(r >> 16);
}
__device__ inline unsigned pk2(float a, float b) {   // [lo=a, hi=b] bf16x2
  __hip_bfloat162 h = __float22bfloat162_rn(float2{a, b});
  union { __hip_bfloat162 h; unsigned u; } v; v.h = h;
  return v.u;
}
// async global->LDS, 16B/lane; lds dest is wave-uniform base (+lane*16 by HW)
__device__ inline void gld16(const void* g, void* l) {
  __builtin_amdgcn_global_load_lds(
      (const __attribute__((address_space(1))) unsigned*)g,
      (__attribute__((address_space(3))) unsigned*)l, 16, 0, 0);
}

__global__ void condlane_prep(const float* __restrict__ params,
                              char* __restrict__ ws) {
  const int inst = blockIdx.x >> 3, part = blockIdx.x & 7;
  const float* __restrict__ p = params + inst * NP;
  char* base = ws + inst * ISTRIDE;
  const int t = threadIdx.x;
  if (part < 4) {            // w0 A-frags (K=64), quarter each
    unsigned short* dst = (unsigned short*)base;
#pragma unroll
    for (int it = 0; it < 4; it++) {
      const int e = (part * 4 + it) * 256 + t;
      const int frag = e >> 9, lane = (e >> 3) & 63, j = e & 7;
      const int m = (frag >> 1) * 16 + (lane & 15);
      const int k = (frag & 1) * 32 + ((lane >> 4) << 3) + j;
      dst[e] = f2bf(p[m * 66 + 2 + k]);
    }
  } else {                   // w1 A-frags quarter (+ vec on part 4)
    unsigned short* dst = (unsigned short*)(base + OFF_W1);
#pragma unroll
    for (int it = 0; it < 4; it++) {
      const int e = ((part - 4) * 4 + it) * 256 + t;
      const int frag = e >> 9, lane = (e >> 3) & 63, j = e & 7;
      const int m = (frag >> 1) * 16 + (lane & 15);
      const int k = (frag & 1) * 32 + ((lane >> 4) << 3) + j;
      dst[e] = f2bf(p[4224 + m * 64 + k]);
    }
    if (part == 4) {
      float* vec = (float*)(base + OFF_VEC);
      if (t < 64) {
        vec[t]       = p[8384 + t];    // b0
        vec[64 + t]  = p[t * 66];      // wx
        vec[128 + t] = p[t * 66 + 1];  // wy
        vec[192 + t] = p[8448 + t];    // b1
        vec[256 + t] = p[8320 + t];    // w2
      } else if (t == 64) vec[320] = p[8512] - 2.19f;
    }
  }
}

__global__ __launch_bounds__(256, 4) void condlane_main(
    const float* __restrict__ x, const char* __restrict__ ws,
    float* __restrict__ out) {
  // [0,18432) weight buf0, [18432,36864) buf1 — no scratch, 4 blocks/CU
  __shared__ __align__(16) char smem[36864];
  const int img = blockIdx.y, bx = blockIdx.x;   // bx: 128-px chunk
  const int tid = threadIdx.x, lane = tid & 63, wave = tid >> 6;
  const int col = lane & 15, q = lane >> 4;
  const char* const wsb = ws + img * 8 * ISTRIDE;

  // per-wave DMA of one instance's weights (4 units/wave + vec on waves 0,1)
  auto dma = [&](int i, char* buf) {
    const char* src = wsb + i * ISTRIDE;
#pragma unroll
    for (int u = 0; u < 4; u++) {
      const int off = (wave * 4 + u) * 1024;
      gld16(src + off + lane * 16, buf + off);
    }
    if (wave < 2) {
      const int off = OFF_VEC + wave * 1024;
      gld16(src + off + lane * 16, buf + off);
    }
  };
  dma(0, smem);   // inst-0 weights in flight during x loads

  // ---- x B-frags straight from global to regs (reused all 8 instances) ----
  bf16x8 bfr[2][2];
  {
    const float* gx = x + img * 64 * HW + bx * 128 + wave * 32;
#pragma unroll
    for (int nt = 0; nt < 2; nt++)
#pragma unroll
      for (int ks = 0; ks < 2; ks++) {
        float f[8];
#pragma unroll
        for (int j = 0; j < 8; j++)
          f[j] = gx[(ks * 32 + q * 8 + j) * HW + nt * 16 + col];
        union { bf16x8 v; unsigned d[4]; } u;
#pragma unroll
        for (int jj = 0; jj < 4; jj++) u.d[jj] = pk2(f[2 * jj], f[2 * jj + 1]);
        bfr[nt][ks] = u.v;
      }
  }
  __syncthreads();   // vmcnt(0)+barrier: inst-0 DMA landed, visible to all

  const float fyv = (float)(bx >> 1);
  const float fx0 = (float)((bx & 1) * 128 + wave * 32 + col);
  float* const outb = out + img * 8 * HW + bx * 128 + wave * 32;

  for (int i = 0; i < 8; i++) {
    char* const wb = smem + (i & 1) * ISTRIDE;
    if (i < 7) dma(i + 1, smem + ((i + 1) & 1) * ISTRIDE);  // async fill
    const float* const vec = (const float*)(wb + OFF_VEC);

    // ---- layer 1: C-init = b0 + wy*fy + wx*fx (exact fp32), K=64 MFMA ----
    f32x4 acc[4][2];
#pragma unroll
    for (int mt = 0; mt < 4; mt++) {
      const int ro = mt * 16 + q * 4;
      const f32x4 b0v = *(const f32x4*)(vec + ro);       // broadcast b128
      const f32x4 wxv = *(const f32x4*)(vec + 64 + ro);
      const f32x4 wyv = *(const f32x4*)(vec + 128 + ro);
      const f32x4 byv = b0v + wyv * fyv;
      acc[mt][0] = byv + wxv * fx0;
      acc[mt][1] = byv + wxv * (fx0 + 16.0f);
    }
#pragma unroll
    for (int mt = 0; mt < 4; mt++) {
      const bf16x8 a0 = *(const bf16x8*)(wb + (mt * 2 + 0) * 1024 + lane * 16);
      const bf16x8 a1 = *(const bf16x8*)(wb + (mt * 2 + 1) * 1024 + lane * 16);
#pragma unroll
      for (int nt = 0; nt < 2; nt++) {
        f32x4 c = __builtin_amdgcn_mfma_f32_16x16x32_bf16(a0, bfr[nt][0],
                                                          acc[mt][nt], 0, 0, 0);
        acc[mt][nt] = __builtin_amdgcn_mfma_f32_16x16x32_bf16(a1, bfr[nt][1],
                                                              c, 0, 0, 0);
      }
    }

    // ---- relu -> bf16 pack in D-layout (reg=(mt,p), lane=q) ----
    unsigned pd[2][4][2];
#pragma unroll
    for (int nt = 0; nt < 2; nt++)
#pragma unroll
      for (int mt = 0; mt < 4; mt++) {
        const f32x4 v = acc[mt][nt];
        pd[nt][mt][0] = pk2(fmaxf(v.x, 0.f), fmaxf(v.y, 0.f));
        pd[nt][mt][1] = pk2(fmaxf(v.z, 0.f), fmaxf(v.w, 0.f));
      }

    // ---- D-layout -> layer-2 B-frags: pure-VALU permlane transpose ----
    // per (nt,ks): 2 chains of {permlane32_swap, permlane16_swap} give the
    // 4 dwords (channels ks*32+q*8+{0..7}, pixel col preserved).
    bf16x8 hbf[2][2];
#pragma unroll
    for (int nt = 0; nt < 2; nt++)
#pragma unroll
      for (int ks = 0; ks < 2; ks++) {
        uint2v r0 = __builtin_amdgcn_permlane32_swap(
            pd[nt][2 * ks][0], pd[nt][2 * ks + 1][0], false, false);
        uint2v s0 = __builtin_amdgcn_permlane16_swap(r0[0], r0[1], false, false);
        uint2v r1 = __builtin_amdgcn_permlane32_swap(
            pd[nt][2 * ks][1], pd[nt][2 * ks + 1][1], false, false);
        uint2v s1 = __builtin_amdgcn_permlane16_swap(r1[0], r1[1], false, false);
        union { unsigned d[4]; bf16x8 v; } u;
        u.d[0] = s0[0];   // ch +0,1  (c2=0,c1=0)
        u.d[1] = s1[0];   // ch +2,3  (c2=0,c1=1)
        u.d[2] = s0[1];   // ch +4,5  (c2=1,c1=0)
        u.d[3] = s1[1];   // ch +6,7  (c2=1,c1=1)
        hbf[nt][ks] = u.v;
      }

    // ---- layer 2 (C=b1) + layer 3 dot(w2, relu) fused per mt ----
    float s0 = 0.f, s1 = 0.f;
#pragma unroll
    for (int mt = 0; mt < 4; mt++) {
      const bf16x8 a0 = *(const bf16x8*)(wb + OFF_W1 + (mt * 2 + 0) * 1024 + lane * 16);
      const bf16x8 a1 = *(const bf16x8*)(wb + OFF_W1 + (mt * 2 + 1) * 1024 + lane * 16);
      const int ro = mt * 16 + q * 4;
      const f32x4 cb  = *(const f32x4*)(vec + 192 + ro);
      const f32x4 w2v = *(const f32x4*)(vec + 256 + ro);
      f32x4 c0 = __builtin_amdgcn_mfma_f32_16x16x32_bf16(a0, hbf[0][0], cb, 0, 0, 0);
      const f32x4 v0 = __builtin_amdgcn_mfma_f32_16x16x32_bf16(a1, hbf[0][1], c0, 0, 0, 0);
      f32x4 c1 = __builtin_amdgcn_mfma_f32_16x16x32_bf16(a0, hbf[1][0], cb, 0, 0, 0);
      const f32x4 v1 = __builtin_amdgcn_mfma_f32_16x16x32_bf16(a1, hbf[1][1], c1, 0, 0, 0);
      s0 += w2v.x * fmaxf(v0.x, 0.f) + w2v.y * fmaxf(v0.y, 0.f) +
            w2v.z * fmaxf(v0.z, 0.f) + w2v.w * fmaxf(v0.w, 0.f);
      s1 += w2v.x * fmaxf(v1.x, 0.f) + w2v.y * fmaxf(v1.y, 0.f) +
            w2v.z * fmaxf(v1.z, 0.f) + w2v.w * fmaxf(v1.w, 0.f);
    }
    const float b2i = vec[320];
    s0 += __shfl_xor(s0, 16, 64); s0 += __shfl_xor(s0, 32, 64);
    s1 += __shfl_xor(s1, 16, 64); s1 += __shfl_xor(s1, 32, 64);
    if (lane < 32)
      outb[i * HW + q * 16 + col] = (q ? s1 : s0) + b2i;

    // barrier: drains DMA (vmcnt0) so buf[(i+1)&1] is ready; also gates WAR
    if (i < 7) __syncthreads();
  }
}

extern "C" void kernel_launch(void* const* d_in, const int* in_sizes, int n_in,
                              void* d_out, int out_size, void* d_ws, size_t ws_size,
                              hipStream_t stream) {
  const float* x      = (const float*)d_in[0];  // [4,64,160,256] fp32
  const float* params = (const float*)d_in[1];  // [32,8513] fp32
  // d_in[2] = num_ins (static 8/img; inst mapping hardcoded)
  float* out = (float*)d_out;

  condlane_prep<<<256, 256, 0, stream>>>(params, (char*)d_ws);   // 590 KB used
  condlane_main<<<dim3(320, 4), 256, 0, stream>>>(x, (const char*)d_ws, out);
}